// Round 7
// baseline (148.596 us; speedup 1.0000x reference)
//
#include <hip/hip_runtime.h>
#include <math.h>

#define N_ORB   1024
#define NTIMES  1024
#define N_FZ    24
#define N_KEZ   6
#define N_TINT  64
#define N_ALPHA 512

#define SL_STRIDE 34   // dword stride: rows 8B-aligned; banks (2su+4tq+i)%32 conflict-free

// Workspace:
//   gT : [N_FZ][N_ALPHA][N_TINT] float  = 3,145,728 B  (grid slice, transposed)
//   Pc : [NTIMES][N_ORB] float2         = 8,388,608 B  {u = s + dalpha, dMagEff}
#define GT_BYTES (N_FZ * N_ALPHA * N_TINT * 4)

// ---------------------------------------------------------------------------
// Kernel 1: fused staging. Blocks 0..191: gT transpose (64tint x 64s tile).
// Blocks 192..1215: Pc build from alpha/dMag, 32x32 (o,t) LDS transpose.
// ---------------------------------------------------------------------------
__global__ __launch_bounds__(256) void stage_inputs(
    const float* __restrict__ grid, const float* __restrict__ kEZs,
    const float* __restrict__ kEZ_val_p, const float* __restrict__ alpha,
    const float* __restrict__ dMag, const float* __restrict__ alphas,
    float* __restrict__ gT, float2* __restrict__ Pc)
{
    __shared__ float lds[64 * 65];          // gT branch; Pc branch aliases

    int b = blockIdx.x;
    if (b < 192) {
        // ---- gT[fz][s][tint] = grid[fz][kez][tint][s] ----
        float kv = kEZ_val_p[0];
        int cnt = 0;
#pragma unroll
        for (int i = 0; i < N_KEZ; ++i) cnt += (kEZs[i] <= kv) ? 1 : 0;
        int kez = cnt - 1;                   // searchsorted(right) - 1
        kez = kez < 0 ? 0 : (kez > N_KEZ - 1 ? N_KEZ - 1 : kez);

        int fz = b >> 3, sc = b & 7;
        int w = threadIdx.x >> 6, lane = threadIdx.x & 63;
        const float* gsrc = grid + ((size_t)fz * N_KEZ + kez) * N_TINT * N_ALPHA;

#pragma unroll
        for (int r = 0; r < 16; ++r) {
            int tint = w * 16 + r;
            lds[tint * 65 + lane] = gsrc[(size_t)tint * N_ALPHA + sc * 64 + lane];
        }
        __syncthreads();
#pragma unroll
        for (int r = 0; r < 16; ++r) {
            int sl = w * 16 + r;
            gT[((size_t)fz * N_ALPHA + sc * 64 + sl) * N_TINT + lane] = lds[lane * 65 + sl];
        }
    } else {
        // ---- Pc[t][o] = {u, dmEff}, 32x32 tile ----
        float* ut = lds;                     // [32][33]
        float* dt = lds + 1056;

        int u = b - 192;                     // 0..1023
        int t0 = (u & 31) * 32, o0 = (u >> 5) * 32;
        int row = threadIdx.x >> 5, col = threadIdx.x & 31;

        float al0 = alphas[0], al1 = alphas[N_ALPHA - 1];
        float la0 = log10f(al0);
        float inv_step = 1.0f / (log10f(alphas[1]) - la0);

#pragma unroll
        for (int r = 0; r < 4; ++r) {
            int ol = r * 8 + row;
            size_t idx = (size_t)(o0 + ol) * NTIMES + t0 + col;
            float a = alpha[idx];
            float d = dMag[idx];
            float a_ind = (log10f(a) - la0) * inv_step;
            int a0i = (int)a_ind;            // trunc toward zero == astype(int32)
            a0i = a0i < 0 ? 0 : (a0i > N_ALPHA - 1 ? N_ALPHA - 1 : a0i);
            float dal = a_ind - (float)a0i;  // vs clipped a0 (faithful)
            int s = a0i > N_ALPHA - 2 ? N_ALPHA - 2 : a0i;   // dynamic_slice clamp
            bool geom = (a >= al0) && (a <= al1);
            float uv = (float)s + dal;       // u packs (s, dalpha); validated R4-R6
            uv = fminf(fmaxf(uv, 0.0f), 510.999f);
            if (!geom) uv = 0.0f;            // dead: dm=INF kills the compare
            ut[ol * 33 + col] = uv;
            dt[ol * 33 + col] = geom ? d : __builtin_inff();
        }
        __syncthreads();
#pragma unroll
        for (int r = 0; r < 4; ++r) {
            int tl = r * 8 + row;
            float2 v;
            v.x = ut[col * 33 + tl];
            v.y = dt[col * 33 + tl];
            Pc[(size_t)(t0 + tl) * N_ORB + o0 + col] = v;
        }
    }
}

// ---------------------------------------------------------------------------
// Kernel 2: block = (t, tint-half), 1024 threads (16 waves). LDS = f0 slice
// for 32 tints ([512 s][34-stride], 69.6 KB) + red -> 2 blocks/CU but
// 32 waves/CU = 8 waves/SIMD (vs 2 in R5/R6) for latency hiding.
// Lane = (orbit-group o 0..7, tint-quad tq 0..7): per instr 8 orbits x
// 32 tints; two ds_read_b128 per iter (rows s, s+1), banks cover all 32
// exactly once per orbit-group -> conflict-free for ANY su. Wave w owns
// orbits [w*64, w*64+64): per iter one 64 B global Pc line. 8 iters total.
// ---------------------------------------------------------------------------
__global__ __launch_bounds__(1024, 8) void pdet_main(
    const float* __restrict__ fZ_vals, const float* __restrict__ fZs,
    const float* __restrict__ gT, const float2* __restrict__ Pc,
    float* __restrict__ out)
{
    __shared__ float sl[N_ALPHA * SL_STRIDE];   // 69,632 B
    __shared__ int   red[16 * 32];              // 2 KB

    int t = blockIdx.x >> 1;
    int h = blockIdx.x & 1;                     // tint half
    int tid = threadIdx.x;

    float lf0 = log10f(fZs[0]);
    float inv_f = 1.0f / (log10f(fZs[1]) - lf0);
    float fi = (log10f(fZ_vals[t]) - lf0) * inv_f;
    int f0 = (int)floorf(fi) + 1;
    f0 = f0 < 0 ? 0 : (f0 > N_FZ - 2 ? N_FZ - 2 : f0);

    const float*  gB = gT + (size_t)f0 * N_ALPHA * N_TINT + h * 32;
    const float2* Pt = Pc + (size_t)t * N_ORB;

    // ---- stage slice half: 512 rows x 32 tints, dst stride 34 ----
#pragma unroll
    for (int it = 0; it < 4; ++it) {
        int idx = it * 1024 + tid;          // 4096 float4 total
        int s = idx >> 3, jj = idx & 7;
        float4 g = *reinterpret_cast<const float4*>(gB + (size_t)s * N_TINT + jj * 4);
        float* dst = &sl[s * SL_STRIDE + jj * 4];
        dst[0] = g.x; dst[1] = g.y; dst[2] = g.z; dst[3] = g.w;
    }
    __syncthreads();

    // ---- main loop: wave w owns orbits [w*64, +64), 8 per iter ----
    int w = tid >> 6, lane = tid & 63;
    int o  = lane >> 3;                     // orbit group 0..7
    int tq = lane & 7;                      // tint quad 0..7
    int tb = tq * 4;

    const float2* Pw = Pt + w * 64 + o;

    int c0 = 0, c1 = 0, c2 = 0, c3 = 0;

#pragma unroll 4
    for (int k = 0; k < 8; ++k) {
        float2 p = Pw[k * 8];               // {u, dmEff}, 8-lane broadcast
        float u = p.x, dm = p.y;
        int su = (int)u;                    // 0..510
        float fr = u - (float)su;
        const float* r = &sl[su * SL_STRIDE + tb];
        float4 g0 = *reinterpret_cast<const float4*>(r);
        float4 g1 = *reinterpret_cast<const float4*>(r + SL_STRIDE);
        c0 += dm < fmaf(fr, g1.x - g0.x, g0.x);
        c1 += dm < fmaf(fr, g1.y - g0.y, g0.y);
        c2 += dm < fmaf(fr, g1.z - g0.z, g0.z);
        c3 += dm < fmaf(fr, g1.w - g0.w, g0.w);
    }

    // reduce across the 8 orbit groups (lane bits 3,4,5)
    c0 += __shfl_xor(c0, 8); c0 += __shfl_xor(c0, 16); c0 += __shfl_xor(c0, 32);
    c1 += __shfl_xor(c1, 8); c1 += __shfl_xor(c1, 16); c1 += __shfl_xor(c1, 32);
    c2 += __shfl_xor(c2, 8); c2 += __shfl_xor(c2, 16); c2 += __shfl_xor(c2, 32);
    c3 += __shfl_xor(c3, 8); c3 += __shfl_xor(c3, 16); c3 += __shfl_xor(c3, 32);

    if (lane < 8) {
        red[w * 32 + tq * 4 + 0] = c0;
        red[w * 32 + tq * 4 + 1] = c1;
        red[w * 32 + tq * 4 + 2] = c2;
        red[w * 32 + tq * 4 + 3] = c3;
    }
    __syncthreads();
    if (tid < 32) {
        int tot = 0;
#pragma unroll
        for (int ww = 0; ww < 16; ++ww) tot += red[ww * 32 + tid];
        out[(size_t)t * N_TINT + h * 32 + tid] = (float)tot * (1.0f / 1024.0f);
    }
}

// ---------------------------------------------------------------------------
extern "C" void kernel_launch(void* const* d_in, const int* in_sizes, int n_in,
                              void* d_out, int out_size, void* d_ws, size_t ws_size,
                              hipStream_t stream) {
    const float* alpha   = (const float*)d_in[0];
    const float* dMag    = (const float*)d_in[1];
    const float* fZ_vals = (const float*)d_in[2];
    const float* kEZ_val = (const float*)d_in[3];
    const float* grid    = (const float*)d_in[4];
    const float* fZs     = (const float*)d_in[5];
    const float* kEZs    = (const float*)d_in[6];
    const float* alphas  = (const float*)d_in[7];
    float*  out = (float*)d_out;

    float*  gT = (float*)d_ws;
    float2* Pc = (float2*)((char*)d_ws + GT_BYTES);

    stage_inputs<<<dim3(192 + 1024), 256, 0, stream>>>(
        grid, kEZs, kEZ_val, alpha, dMag, alphas, gT, Pc);
    pdet_main<<<dim3(NTIMES * 2), 1024, 0, stream>>>(fZ_vals, fZs, gT, Pc, out);
}

// Round 8
// 109.795 us; speedup vs baseline: 1.3534x; 1.3534x over previous
//
#include <hip/hip_runtime.h>
#include <math.h>

#define N_ORB   1024
#define NTIMES  1024
#define N_FZ    24
#define N_KEZ   6
#define N_TINT  64
#define N_ALPHA 512

#define SL_STRIDE 34   // dword stride: rows 8B-aligned; inner-loop banks conflict-free

// Workspace:
//   gT    : [N_FZ][N_ALPHA][N_TINT] float = 3,145,728 B (grid slice, transposed)
//   Pc    : [NTIMES][N_ORB] float2        = 8,388,608 B {u = s + dalpha, dMagEff}
//   tOrdF : [NTIMES] int                  = 4,096 B     (f0<<10 | t, f0-sorted)
#define GT_BYTES (N_FZ * N_ALPHA * N_TINT * 4)
#define PC_BYTES (NTIMES * N_ORB * 8)

// ---------------------------------------------------------------------------
// Kernel 1: fused staging. Blocks 0..191: gT transpose. Blocks 192..1215:
// Pc build (32x32 LDS transpose). Block 1216: counting-sort t by f0.
// ---------------------------------------------------------------------------
__global__ __launch_bounds__(256) void stage_inputs(
    const float* __restrict__ grid, const float* __restrict__ kEZs,
    const float* __restrict__ kEZ_val_p, const float* __restrict__ alpha,
    const float* __restrict__ dMag, const float* __restrict__ alphas,
    const float* __restrict__ fZ_vals, const float* __restrict__ fZs,
    float* __restrict__ gT, float2* __restrict__ Pc, int* __restrict__ tOrdF)
{
    __shared__ float lds[64 * 65];          // each branch aliases as needed

    int b = blockIdx.x;
    int tid = threadIdx.x;
    if (b < 192) {
        // ---- gT[fz][s][tint] = grid[fz][kez][tint][s] ----
        float kv = kEZ_val_p[0];
        int cnt = 0;
#pragma unroll
        for (int i = 0; i < N_KEZ; ++i) cnt += (kEZs[i] <= kv) ? 1 : 0;
        int kez = cnt - 1;                   // searchsorted(right) - 1
        kez = kez < 0 ? 0 : (kez > N_KEZ - 1 ? N_KEZ - 1 : kez);

        int fz = b >> 3, sc = b & 7;
        int w = tid >> 6, lane = tid & 63;
        const float* gsrc = grid + ((size_t)fz * N_KEZ + kez) * N_TINT * N_ALPHA;

#pragma unroll
        for (int r = 0; r < 16; ++r) {
            int tint = w * 16 + r;
            lds[tint * 65 + lane] = gsrc[(size_t)tint * N_ALPHA + sc * 64 + lane];
        }
        __syncthreads();
#pragma unroll
        for (int r = 0; r < 16; ++r) {
            int sl = w * 16 + r;
            gT[((size_t)fz * N_ALPHA + sc * 64 + sl) * N_TINT + lane] = lds[lane * 65 + sl];
        }
    } else if (b < 1216) {
        // ---- Pc[t][o] = {u, dmEff}, 32x32 tile ----
        float* ut = lds;                     // [32][33]
        float* dt = lds + 1056;

        int u = b - 192;                     // 0..1023
        int t0 = (u & 31) * 32, o0 = (u >> 5) * 32;
        int row = tid >> 5, col = tid & 31;

        float al0 = alphas[0], al1 = alphas[N_ALPHA - 1];
        float la0 = log10f(al0);
        float inv_step = 1.0f / (log10f(alphas[1]) - la0);

#pragma unroll
        for (int r = 0; r < 4; ++r) {
            int ol = r * 8 + row;
            size_t idx = (size_t)(o0 + ol) * NTIMES + t0 + col;
            float a = alpha[idx];
            float d = dMag[idx];
            float a_ind = (log10f(a) - la0) * inv_step;
            int a0i = (int)a_ind;            // trunc toward zero == astype(int32)
            a0i = a0i < 0 ? 0 : (a0i > N_ALPHA - 1 ? N_ALPHA - 1 : a0i);
            float dal = a_ind - (float)a0i;  // vs clipped a0 (faithful)
            int s = a0i > N_ALPHA - 2 ? N_ALPHA - 2 : a0i;   // dynamic_slice clamp
            bool geom = (a >= al0) && (a <= al1);
            float uv = (float)s + dal;       // u packs (s, dalpha); validated R4-R7
            uv = fminf(fmaxf(uv, 0.0f), 510.999f);
            if (!geom) uv = 0.0f;            // dead: dm=INF kills the compare
            ut[ol * 33 + col] = uv;
            dt[ol * 33 + col] = geom ? d : __builtin_inff();
        }
        __syncthreads();
#pragma unroll
        for (int r = 0; r < 4; ++r) {
            int tl = r * 8 + row;
            float2 v;
            v.x = ut[col * 33 + tl];
            v.y = dt[col * 33 + tl];
            Pc[(size_t)(t0 + tl) * N_ORB + o0 + col] = v;
        }
    } else {
        // ---- counting-sort t by f0 (unstable; permutation-invariant output) ----
        int* ih   = (int*)lds;               // hist[0..22]
        int* base = (int*)lds + 32;          // cursors
        if (tid < 32) ih[tid] = 0;
        __syncthreads();

        float lf0 = log10f(fZs[0]);
        float inv_f = 1.0f / (log10f(fZs[1]) - lf0);
        int f0v[4], tv[4];
#pragma unroll
        for (int k = 0; k < 4; ++k) {
            int t = k * 256 + tid;
            float fi = (log10f(fZ_vals[t]) - lf0) * inv_f;
            int f0 = (int)floorf(fi) + 1;
            f0 = f0 < 0 ? 0 : (f0 > N_FZ - 2 ? N_FZ - 2 : f0);
            f0v[k] = f0; tv[k] = t;
            atomicAdd(&ih[f0], 1);
        }
        __syncthreads();
        if (tid == 0) {
            int run = 0;
#pragma unroll
            for (int j = 0; j < 23; ++j) { base[j] = run; run += ih[j]; }
        }
        __syncthreads();
#pragma unroll
        for (int k = 0; k < 4; ++k) {
            int pos = atomicAdd(&base[f0v[k]], 1);
            tOrdF[pos] = (f0v[k] << 10) | tv[k];
        }
    }
}

// ---------------------------------------------------------------------------
// Kernel 2: block = (t-chunk of 4 f0-sorted t's, tint-half), 256 threads.
// Stage the f0 slice for 32 tints into LDS ([512 s][34-stride], 69.6 KB,
// 2 blocks/CU) ONCE per f0 (t's are f0-sorted -> ~1 staging per block,
// rare boundary re-stage). Inner loop per t (R6-proven): lane = (orbit-
// group o 0..3, tint-pair tp 0..15); per iter one 32 B global Pc region
// (broadcast, 8-deep pipelined) + one ds_read2_b64 (rows s, s+1; banks
// 2su+2tp+i cover all 32 once per group -> conflict-free for any su).
// ---------------------------------------------------------------------------
__global__ __launch_bounds__(256) void pdet_main(
    const int* __restrict__ tOrdF, const float* __restrict__ gT,
    const float2* __restrict__ Pc, float* __restrict__ out)
{
    __shared__ float sl[N_ALPHA * SL_STRIDE];   // 69,632 B
    __shared__ int   red[128];

    int bb = blockIdx.x >> 1;
    int h  = blockIdx.x & 1;                    // tint half
    int tid = threadIdx.x;
    int w = tid >> 6, lane = tid & 63;
    int o  = lane >> 4;                         // orbit group 0..3
    int tp = lane & 15;                         // tint pair 0..15

    int curF0 = -1;

    for (int i = 0; i < 4; ++i) {
        int e  = tOrdF[bb * 4 + i];             // uniform across block
        int t  = e & 1023;
        int f0 = e >> 10;

        if (f0 != curF0) {
            __syncthreads();                    // protect sl from prior t's readers
            const float* gB = gT + (size_t)f0 * N_ALPHA * N_TINT + h * 32;
#pragma unroll
            for (int it = 0; it < 16; ++it) {
                int idx = it * 256 + tid;       // 4096 float4 total
                int s = idx >> 3, jj = idx & 7;
                float4 g = *reinterpret_cast<const float4*>(gB + (size_t)s * N_TINT + jj * 4);
                float* dst = &sl[s * SL_STRIDE + jj * 4];
                dst[0] = g.x; dst[1] = g.y; dst[2] = g.z; dst[3] = g.w;
            }
            __syncthreads();
            curF0 = f0;
        }

        const float2* Pg = Pc + (size_t)t * N_ORB + w * 256 + o;
        int c0 = 0, c1 = 0;

#pragma unroll 8
        for (int k = 0; k < 64; ++k) {
            float2 p = Pg[k * 4];               // {u, dmEff}, 16-lane broadcast
            float u = p.x, dm = p.y;
            int su = (int)u;                    // 0..510
            float fr = u - (float)su;
            const float* r = &sl[su * SL_STRIDE + tp * 2];
            float g00 = r[0];
            float g01 = r[1];
            float g10 = r[SL_STRIDE];           // row s+1 (ds_read2_b64)
            float g11 = r[SL_STRIDE + 1];
            c0 += dm < fmaf(fr, g10 - g00, g00);
            c1 += dm < fmaf(fr, g11 - g01, g01);
        }

        // reduce across the 4 orbit groups (lane bits 4,5)
        c0 += __shfl_xor(c0, 16); c0 += __shfl_xor(c0, 32);
        c1 += __shfl_xor(c1, 16); c1 += __shfl_xor(c1, 32);
        if (lane < 16) {
            red[w * 32 + tp * 2]     = c0;
            red[w * 32 + tp * 2 + 1] = c1;
        }
        __syncthreads();
        if (tid < 32) {
            int tot = red[tid] + red[32 + tid] + red[64 + tid] + red[96 + tid];
            out[(size_t)t * N_TINT + h * 32 + tid] = (float)tot * (1.0f / 1024.0f);
        }
        __syncthreads();                        // red reused by next t
    }
}

// ---------------------------------------------------------------------------
extern "C" void kernel_launch(void* const* d_in, const int* in_sizes, int n_in,
                              void* d_out, int out_size, void* d_ws, size_t ws_size,
                              hipStream_t stream) {
    const float* alpha   = (const float*)d_in[0];
    const float* dMag    = (const float*)d_in[1];
    const float* fZ_vals = (const float*)d_in[2];
    const float* kEZ_val = (const float*)d_in[3];
    const float* grid    = (const float*)d_in[4];
    const float* fZs     = (const float*)d_in[5];
    const float* kEZs    = (const float*)d_in[6];
    const float* alphas  = (const float*)d_in[7];
    float*  out = (float*)d_out;

    float*  gT    = (float*)d_ws;
    float2* Pc    = (float2*)((char*)d_ws + GT_BYTES);
    int*    tOrdF = (int*)((char*)d_ws + GT_BYTES + PC_BYTES);

    stage_inputs<<<dim3(1217), 256, 0, stream>>>(
        grid, kEZs, kEZ_val, alpha, dMag, alphas, fZ_vals, fZs, gT, Pc, tOrdF);
    pdet_main<<<dim3(512), 256, 0, stream>>>(tOrdF, gT, Pc, out);
}